// Round 2
// baseline (434.346 us; speedup 1.0000x reference)
//
#include <hip/hip_runtime.h>
#include <stdint.h>

#define T_LEN 512
#define IN0   9
#define H     56
#define BG    8
#define NW    14
#define NTH   (NW * 64)        // 896 threads, 14 waves
#define NBLK  256

typedef __attribute__((ext_vector_type(8))) short bfrag;   // 8 bf16
typedef __attribute__((ext_vector_type(4))) float ffrag;   // 4 fp32

#define MFMA(a,b,c) __builtin_amdgcn_mfma_f32_16x16x32_bf16((a),(b),(c),0,0,0)

__device__ __forceinline__ uint32_t bf16hi(float x) {
  uint32_t u = __float_as_uint(x);
  return (u + 0x7FFFu + ((u >> 16) & 1u)) & 0xFFFF0000u;
}
// RNE both halves (weights, init-time only)
__device__ __forceinline__ void split_bf16(float x, short& hs, short& ls) {
  uint32_t hb = bf16hi(x);
  float lf = x - __uint_as_float(hb);
  hs = (short)(hb >> 16);
  ls = (short)(bf16hi(lf) >> 16);
}
// RNE hi, truncated lo (loop-time)
__device__ __forceinline__ void split_bf16t(float x, short& hs, short& ls) {
  uint32_t hb = bf16hi(x);
  float lf = x - __uint_as_float(hb);
  hs = (short)(hb >> 16);
  ls = (short)(__float_as_uint(lf) >> 16);
}
// v = v + lane(v ^ 8), via DPP row_ror:8 (xor-8 == ror-8 within 16-lane rows)
__device__ __forceinline__ float dpp8_add(float v) {
  int p = __builtin_amdgcn_update_dpp(0, __float_as_int(v), 0x128, 0xF, 0xF, true);
  return v + __int_as_float(p);
}
__device__ __forceinline__ float rcp_f(float v)  { return __builtin_amdgcn_rcpf(v); }
__device__ __forceinline__ float sigm_f(float v) { return rcp_f(1.0f + __expf(-v)); }
__device__ __forceinline__ float tanh_f(float v) { return 1.0f - 2.0f * rcp_f(1.0f + __expf(2.0f * v)); }

__global__ __launch_bounds__(NTH, 4)
void lstm_mfma9(const float* __restrict__ x,
                const float* __restrict__ w_ih0, const float* __restrict__ w_hh0,
                const float* __restrict__ b_ih0, const float* __restrict__ b_hh0,
                const float* __restrict__ w_ih1, const float* __restrict__ w_hh1,
                const float* __restrict__ b_ih1, const float* __restrict__ b_hh1,
                const float* __restrict__ fc1_w, const float* __restrict__ fc1_b,
                const float* __restrict__ fc2_w, const float* __restrict__ fc2_b,
                float* __restrict__ out)
{
  // h-state as MFMA B-operand: B[k = h-element j (k56..63 = x)][n = batch-slot]
  // cols 0..7 = hi, cols 8..15 = lo residual. Fragment-linear.
  // x lives entirely in LDS (prefill): xfS = per-t fragment rows k=56..63
  // (hi+lo cols), x8S = per-t x[8] plane (fp32). Main loop: ZERO global memory.
  // Numerics are verbatim the 428us kernel (bit-exact path).
  __shared__ __align__(16) short hbufS[4 * 1024];     //  8 KiB: h ring (4 regions)
  __shared__ __align__(16) short xfS[T_LEN * 128];    // 128 KiB: x fragments
  __shared__ __align__(16) float x8S[T_LEN * BG];     //  16 KiB: x[8]
  __shared__ float sF[BG * H];
  __shared__ float sY[BG * 28];

  const int tid  = threadIdx.x;
  const int lane = tid & 63;
  const int w    = tid >> 6;
  const int c16  = lane & 15;
  const int quad = lane >> 4;

  const int np   = 16 * w + c16;       // n' = 4j+g (A-operand M index)
  const int jb   = np >> 2, gb = np & 3;
  const int wrow = gb * H + jb;

  for (int i = tid; i < 2048; i += NTH) ((int*)hbufS)[i] = 0;

  // ---- A-fragments (weights): A[m=c16][k=quad*8+jj] ----
  bfrag B0h[2], B0l[2], Buh[2], Bhh[2];
  #pragma unroll
  for (int s = 0; s < 2; ++s) {
    union { short sh[8]; bfrag v; } a0h, a0l, auh, ahh;
    #pragma unroll
    for (int jj = 0; jj < 8; ++jj) {
      const int k = 32 * s + quad * 8 + jj;
      const float w0 = (k < H) ? w_hh0[wrow * H + k] : w_ih0[wrow * IN0 + (k - 56)];
      const float wu = (k < H) ? w_ih1[wrow * H + k] : 0.0f;
      const float wh = (k < H) ? w_hh1[wrow * H + k] : 0.0f;
      split_bf16(w0, a0h.sh[jj], a0l.sh[jj]);
      short dum;
      split_bf16(wu, auh.sh[jj], dum);   // RNE hi only
      split_bf16(wh, ahh.sh[jj], dum);
    }
    B0h[s] = a0h.v; B0l[s] = a0l.v;
    Buh[s] = auh.v; Bhh[s] = ahh.v;
  }

  // D rows m = 4*quad + r -> gate g=r of j4 = 4w+quad. Bias rides C on hi cols.
  const int j4 = 4 * w + quad;
  ffrag bias0f, bias1f;
  #pragma unroll
  for (int r = 0; r < 4; ++r) {
    const float v0 = b_ih0[r * H + j4] + b_hh0[r * H + j4];
    const float v1 = b_ih1[r * H + j4] + b_hh1[r * H + j4];
    bias0f[r] = (c16 < 8) ? v0 : 0.0f;
    bias1f[r] = (c16 < 8) ? v1 : 0.0f;
  }
  const ffrag zerof = { 0.f, 0.f, 0.f, 0.f };

  // act identity: lay=0 (c16<8) -> layer1 element (b, j4); lay=1 -> layer0
  const int lay = (lane >> 3) & 1;
  const int b   = lane & 7;
  float wx8a[4];
  #pragma unroll
  for (int r = 0; r < 4; ++r)
    wx8a[r] = lay ? w_ih0[(r * H + j4) * IN0 + 8] : 0.0f;

  // h store offsets (shorts, relative to hbufS)
  const int kk   = j4 & 31;
  const int offE = (j4 >> 5) * 512 + ((kk >> 3) * 16 + b) * 8 + (kk & 7);
  short* const hp0 = hbufS + (lay ? 0 : 3 * 1024) + offE;
  short* const hp1 = hbufS + (lay ? 1 * 1024 : 2 * 1024) + offE;

  // ---- x prefill: all 512 timesteps into LDS (fragment layout + x8 plane) ----
  for (int item = tid; item < T_LEN * BG; item += NTH) {
    const int t  = item & (T_LEN - 1);
    const int bb = item >> 9;
    const float* xr = x + ((size_t)(blockIdx.x * BG + bb) * T_LEN + t) * IN0;
    union { short s[8]; bfrag v; } hi, lo;
    #pragma unroll
    for (int q = 0; q < 8; ++q) split_bf16t(xr[q], hi.s[q], lo.s[q]);
    *(bfrag*)((char*)xfS + (size_t)t * 256 + bb * 16)       = hi.v;
    *(bfrag*)((char*)xfS + (size_t)t * 256 + (bb + 8) * 16) = lo.v;
    x8S[t * 8 + bb] = xr[8];
  }

  // ---- per-lane LDS read pointers ----
  const char* const hB = (const char*)hbufS;
  const char* const pU0_0 = hB + 2048 + lane * 16;   // sB[1] k0..31
  const char* const pU0_1 = hB +        lane * 16;   // sB[0]
  const char* const pH0_0 = hB + 4096 + lane * 16;   // sB[2]
  const char* const pH1_0 = hB + 5120 + lane * 16;
  const char* const pH0_1 = hB + 6144 + lane * 16;   // sB[3]
  const char* const pH1_1 = hB + 7168 + lane * 16;
  // U1: quads 0-2 read h rows k32..55 from ring; quad 3 reads x(t) plane
  const char* pU1_0 = (quad == 3) ? ((const char*)xfS + 256 * 1 + c16 * 16)
                                  : (hB + 3072 + lane * 16);
  const char* pU1_1 = (quad == 3) ? ((const char*)xfS + 256 * 2 + c16 * 16)
                                  : (hB + 1024 + lane * 16);
  const char* px8_0 = (const char*)x8S + 32 * 1 + b * 4;
  const char* px8_1 = (const char*)x8S + 32 * 2 + b * 4;
  const int incU1 = (quad == 3) ? 512 : 0;

  float cst = 0.f;                     // lay0: c1, lay1: c0
  __syncthreads();                     // zeros + x prefill visible

  // ---- prologue: L0(t=0); U0 and h-part of U1 are zeros, x(0) from xfS ----
  {
    const bfrag U0 = *(const bfrag*)(hB + lane * 16);                  // zeros
    const char* pU1p = (quad == 3) ? ((const char*)xfS + c16 * 16)
                                   : (hB + 1024 + lane * 16);          // zeros
    const bfrag U1 = *(const bfrag*)pU1p;
    const float x8v = x8S[b];
    ffrag a0 = MFMA(B0h[0], U0, bias0f);
    a0 = MFMA(B0h[1], U1, a0);
    a0 = MFMA(B0l[0], U0, a0);
    a0 = MFMA(B0l[1], U1, a0);
    float s0[4];
    #pragma unroll
    for (int r = 0; r < 4; ++r) s0[r] = dpp8_add(a0[r]);
    if (lay) {
      const float gi = fmaf(wx8a[0], x8v, s0[0]);
      const float gf = fmaf(wx8a[1], x8v, s0[1]);
      const float gg = fmaf(wx8a[2], x8v, s0[2]);
      const float go = fmaf(wx8a[3], x8v, s0[3]);
      const float iv = sigm_f(gi), fv = sigm_f(gf);
      const float gv = tanh_f(gg), ov = sigm_f(go);
      cst = fmaf(fv, cst, iv * gv);
      const float hv = ov * tanh_f(cst);
      short hs, hl; split_bf16t(hv, hs, hl);
      hp1[0] = hs; hp1[64] = hl;       // h0(0) -> sB[1]
    }
    __syncthreads();
  }

#define REGION(RR, L0PART, LASTR)                                               \
  {                                                                             \
    const bfrag U0 = *(const bfrag*)pU0_##RR;                                   \
    const bfrag U1 = *(const bfrag*)pU1_##RR;                                   \
    const bfrag H0 = *(const bfrag*)pH0_##RR;                                   \
    const bfrag H1 = *(const bfrag*)pH1_##RR;                                   \
    ffrag a0;                                                                   \
    float x8v = 0.0f;                                                           \
    if (L0PART) {                                                               \
      x8v = *(const float*)px8_##RR;                                            \
      a0 = MFMA(B0h[0], U0, bias0f);                                            \
      a0 = MFMA(B0h[1], U1, a0);                                                \
      a0 = MFMA(B0l[0], U0, a0);                                                \
      a0 = MFMA(B0l[1], U1, a0);                                                \
    }                                                                           \
    /* L1: hi-weight passes only */                                             \
    ffrag aH = MFMA(Bhh[0], H0, bias1f);                                        \
    aH = MFMA(Bhh[1], H1, aH);                                                  \
    ffrag aU = MFMA(Buh[0], U0, zerof);                                         \
    aU = MFMA(Buh[1], U1, aU);                                                  \
    if (!LASTR) {                                                               \
      float sv[4];                                                              \
      _Pragma("unroll")                                                         \
      for (int r = 0; r < 4; ++r) {                                             \
        const float s1 = dpp8_add(aH[r] + aU[r]);                               \
        const float s0 = dpp8_add(a0[r]);                                       \
        sv[r] = lay ? s0 : s1;                                                  \
      }                                                                         \
      const float gi = fmaf(wx8a[0], x8v, sv[0]);                               \
      const float gf = fmaf(wx8a[1], x8v, sv[1]);                               \
      const float gg = fmaf(wx8a[2], x8v, sv[2]);                               \
      const float go = fmaf(wx8a[3], x8v, sv[3]);                               \
      const float iv = sigm_f(gi), fv = sigm_f(gf);                             \
      const float gv = tanh_f(gg), ov = sigm_f(go);                             \
      cst = fmaf(fv, cst, iv * gv);                                             \
      const float hv = ov * tanh_f(cst);                                        \
      short hs, hl; split_bf16t(hv, hs, hl);                                    \
      short* hb2 = (RR == 0) ? hp0 : hp1;                                       \
      hb2[0] = hs; hb2[64] = hl;                                                \
    } else {                                                                    \
      float s1[4];                                                              \
      _Pragma("unroll")                                                         \
      for (int r = 0; r < 4; ++r) s1[r] = dpp8_add(aH[r] + aU[r]);              \
      if (lay == 0) {                                                           \
        const float iv = sigm_f(s1[0]), fv = sigm_f(s1[1]);                     \
        const float gv = tanh_f(s1[2]), ov = sigm_f(s1[3]);                     \
        cst = fmaf(fv, cst, iv * gv);                                           \
        sF[b * H + j4] = ov * tanh_f(cst);                                      \
      }                                                                         \
    }                                                                           \
    __syncthreads();                                                            \
  }

  // main: 255 iters x 2 regions (t=1..510), then t=511, then L1-only tail
  for (int it = 0; it < 255; ++it) {
    REGION(0, 1, 0)
    REGION(1, 1, 0)
    pU1_0 += incU1; pU1_1 += incU1;
    px8_0 += 64;    px8_1 += 64;
  }
  REGION(0, 1, 0)
  // pU1_1 would be one timestep past xfS (t=512): pull it back in-bounds.
  // Data is irrelevant (Buh rows k>=56 are zero) but OOB garbage risks 0*Inf=NaN.
  pU1_1 -= incU1;
  REGION(1, 0, 1)
#undef REGION

  // ---- FC head on final h1 ----
  if (tid < 28 * BG) {
    const int m  = tid >> 3;
    const int bb = tid & 7;
    float acc = fc1_b[m];
    const float4* w4 = (const float4*)(fc1_w + m * H);
    const float4* h4 = (const float4*)(sF + bb * H);
    #pragma unroll
    for (int qq = 0; qq < H / 4; ++qq) {
      const float4 wv4 = w4[qq], hv4 = h4[qq];
      acc = fmaf(wv4.x, hv4.x, acc);
      acc = fmaf(wv4.y, hv4.y, acc);
      acc = fmaf(wv4.z, hv4.z, acc);
      acc = fmaf(wv4.w, hv4.w, acc);
    }
    sY[bb * 28 + m] = fmaxf(acc, 0.0f);
  }
  __syncthreads();
  if (tid < BG) {
    float acc = fc2_b[0];
    #pragma unroll
    for (int m = 0; m < 28; ++m)
      acc = fmaf(fc2_w[m], sY[tid * 28 + m], acc);
    out[blockIdx.x * BG + tid] = acc;
  }
}

extern "C" void kernel_launch(void* const* d_in, const int* in_sizes, int n_in,
                              void* d_out, int out_size, void* d_ws, size_t ws_size,
                              hipStream_t stream)
{
  const float* x     = (const float*)d_in[0];
  const float* w_ih0 = (const float*)d_in[1];
  const float* w_hh0 = (const float*)d_in[2];
  const float* b_ih0 = (const float*)d_in[3];
  const float* b_hh0 = (const float*)d_in[4];
  const float* w_ih1 = (const float*)d_in[5];
  const float* w_hh1 = (const float*)d_in[6];
  const float* b_ih1 = (const float*)d_in[7];
  const float* b_hh1 = (const float*)d_in[8];
  const float* fc1_w = (const float*)d_in[9];
  const float* fc1_b = (const float*)d_in[10];
  const float* fc2_w = (const float*)d_in[11];
  const float* fc2_b = (const float*)d_in[12];
  float* out = (float*)d_out;

  lstm_mfma9<<<NBLK, NTH, 0, stream>>>(
      x, w_ih0, w_hh0, b_ih0, b_hh0, w_ih1, w_hh1, b_ih1, b_hh1,
      fc1_w, fc1_b, fc2_w, fc2_b, out);
}

// Round 3
// 425.781 us; speedup vs baseline: 1.0201x; 1.0201x over previous
//
#include <hip/hip_runtime.h>
#include <stdint.h>

#define T_LEN 512
#define IN0   9
#define H     56
#define BG    8
#define NW    14
#define NTH   (NW * 64)        // 896 threads, 14 waves
#define NBLK  256

typedef __attribute__((ext_vector_type(8))) short bfrag;   // 8 bf16
typedef __attribute__((ext_vector_type(4))) float ffrag;   // 4 fp32

#define MFMA(a,b,c) __builtin_amdgcn_mfma_f32_16x16x32_bf16((a),(b),(c),0,0,0)

__device__ __forceinline__ uint32_t bf16hi(float x) {
  uint32_t u = __float_as_uint(x);
  return (u + 0x7FFFu + ((u >> 16) & 1u)) & 0xFFFF0000u;
}
// RNE both halves (weights, init-time only)
__device__ __forceinline__ void split_bf16(float x, short& hs, short& ls) {
  uint32_t hb = bf16hi(x);
  float lf = x - __uint_as_float(hb);
  hs = (short)(hb >> 16);
  ls = (short)(bf16hi(lf) >> 16);
}
// RNE hi, truncated lo (loop-time)
__device__ __forceinline__ void split_bf16t(float x, short& hs, short& ls) {
  uint32_t hb = bf16hi(x);
  float lf = x - __uint_as_float(hb);
  hs = (short)(hb >> 16);
  ls = (short)(__float_as_uint(lf) >> 16);
}
// returns lane(v ^ 8), via DPP row_ror:8 (xor-8 == ror-8 within 16-lane rows)
__device__ __forceinline__ float dpp8(float v) {
  return __int_as_float(__builtin_amdgcn_update_dpp(0, __float_as_int(v), 0x128, 0xF, 0xF, true));
}
__device__ __forceinline__ float rcp_f(float v)  { return __builtin_amdgcn_rcpf(v); }
__device__ __forceinline__ float sigm_f(float v) { return rcp_f(1.0f + __expf(-v)); }
__device__ __forceinline__ float tanh_f(float v) { return 1.0f - 2.0f * rcp_f(1.0f + __expf(2.0f * v)); }

__global__ __launch_bounds__(NTH, 4)
void lstm_mfma10(const float* __restrict__ x,
                 const float* __restrict__ w_ih0, const float* __restrict__ w_hh0,
                 const float* __restrict__ b_ih0, const float* __restrict__ b_hh0,
                 const float* __restrict__ w_ih1, const float* __restrict__ w_hh1,
                 const float* __restrict__ b_ih1, const float* __restrict__ b_hh1,
                 const float* __restrict__ fc1_w, const float* __restrict__ fc1_b,
                 const float* __restrict__ fc2_w, const float* __restrict__ fc2_b,
                 float* __restrict__ out)
{
  // h-state as MFMA B-operand: B[k = h-element j (k56..63 = x)][n = batch-slot]
  // cols 0..7 = hi, cols 8..15 = lo residual. Fragment-linear.
  // x lives entirely in LDS (prefill); main loop has ZERO global memory ops.
  // setprio(1) around the MFMA cluster: waves that finish their MFMAs drop to
  // prio 0 and run activations while other waves' MFMAs drain the matrix pipe
  // (breaks the round-robin convoy that serialized matrix and VALU phases).
  __shared__ __align__(16) short hbufS[4 * 1024];     //  8 KiB: h ring (4 regions)
  __shared__ __align__(16) short xfS[T_LEN * 128];    // 128 KiB: x fragments
  __shared__ __align__(16) float x8S[T_LEN * BG];     //  16 KiB: x[8]
  __shared__ float sF[BG * H];
  __shared__ float sY[BG * 28];

  const int tid  = threadIdx.x;
  const int lane = tid & 63;
  const int w    = tid >> 6;
  const int c16  = lane & 15;
  const int quad = lane >> 4;

  const int np   = 16 * w + c16;       // n' = 4j+g (A-operand M index)
  const int jb   = np >> 2, gb = np & 3;
  const int wrow = gb * H + jb;

  for (int i = tid; i < 2048; i += NTH) ((int*)hbufS)[i] = 0;

  // ---- A-fragments (weights): A[m=c16][k=quad*8+jj] ----
  bfrag B0h[2], B0l[2], Buh[2], Bhh[2];
  #pragma unroll
  for (int s = 0; s < 2; ++s) {
    union { short sh[8]; bfrag v; } a0h, a0l, auh, ahh;
    #pragma unroll
    for (int jj = 0; jj < 8; ++jj) {
      const int k = 32 * s + quad * 8 + jj;
      const float w0 = (k < H) ? w_hh0[wrow * H + k] : w_ih0[wrow * IN0 + (k - 56)];
      const float wu = (k < H) ? w_ih1[wrow * H + k] : 0.0f;
      const float wh = (k < H) ? w_hh1[wrow * H + k] : 0.0f;
      split_bf16(w0, a0h.sh[jj], a0l.sh[jj]);
      short dum;
      split_bf16(wu, auh.sh[jj], dum);   // RNE hi only
      split_bf16(wh, ahh.sh[jj], dum);
    }
    B0h[s] = a0h.v; B0l[s] = a0l.v;
    Buh[s] = auh.v; Bhh[s] = ahh.v;
  }

  // D rows m = 4*quad + r -> gate g=r of j4 = 4w+quad. Bias rides C on hi cols.
  const int j4 = 4 * w + quad;
  ffrag bias0f, bias1f;
  #pragma unroll
  for (int r = 0; r < 4; ++r) {
    const float v0 = b_ih0[r * H + j4] + b_hh0[r * H + j4];
    const float v1 = b_ih1[r * H + j4] + b_hh1[r * H + j4];
    bias0f[r] = (c16 < 8) ? v0 : 0.0f;
    bias1f[r] = (c16 < 8) ? v1 : 0.0f;
  }
  const ffrag zerof = { 0.f, 0.f, 0.f, 0.f };

  // act identity: lay=0 (c16<8) -> layer1 element (b, j4); lay=1 -> layer0
  const int lay = (lane >> 3) & 1;
  const int b   = lane & 7;
  float wx8a[4];
  #pragma unroll
  for (int r = 0; r < 4; ++r)
    wx8a[r] = lay ? w_ih0[(r * H + j4) * IN0 + 8] : 0.0f;

  // h store offsets (shorts, relative to hbufS)
  const int kk   = j4 & 31;
  const int offE = (j4 >> 5) * 512 + ((kk >> 3) * 16 + b) * 8 + (kk & 7);
  short* const hp0 = hbufS + (lay ? 0 : 3 * 1024) + offE;
  short* const hp1 = hbufS + (lay ? 1 * 1024 : 2 * 1024) + offE;

  // ---- x prefill: all 512 timesteps into LDS (fragment layout + x8 plane) ----
  for (int item = tid; item < T_LEN * BG; item += NTH) {
    const int t  = item & (T_LEN - 1);
    const int bb = item >> 9;
    const float* xr = x + ((size_t)(blockIdx.x * BG + bb) * T_LEN + t) * IN0;
    union { short s[8]; bfrag v; } hi, lo;
    #pragma unroll
    for (int q = 0; q < 8; ++q) split_bf16t(xr[q], hi.s[q], lo.s[q]);
    *(bfrag*)((char*)xfS + (size_t)t * 256 + bb * 16)       = hi.v;
    *(bfrag*)((char*)xfS + (size_t)t * 256 + (bb + 8) * 16) = lo.v;
    x8S[t * 8 + bb] = xr[8];
  }

  // ---- per-lane LDS read pointers ----
  const char* const hB = (const char*)hbufS;
  const char* const pU0_0 = hB + 2048 + lane * 16;   // sB[1] k0..31
  const char* const pU0_1 = hB +        lane * 16;   // sB[0]
  const char* const pH0_0 = hB + 4096 + lane * 16;   // sB[2]
  const char* const pH1_0 = hB + 5120 + lane * 16;
  const char* const pH0_1 = hB + 6144 + lane * 16;   // sB[3]
  const char* const pH1_1 = hB + 7168 + lane * 16;
  // U1: quads 0-2 read h rows k32..55 from ring; quad 3 reads x(t) plane
  const char* pU1_0 = (quad == 3) ? ((const char*)xfS + 256 * 1 + c16 * 16)
                                  : (hB + 3072 + lane * 16);
  const char* pU1_1 = (quad == 3) ? ((const char*)xfS + 256 * 2 + c16 * 16)
                                  : (hB + 1024 + lane * 16);
  const char* px8_0 = (const char*)x8S + 32 * 1 + b * 4;
  const char* px8_1 = (const char*)x8S + 32 * 2 + b * 4;
  const int incU1 = (quad == 3) ? 512 : 0;

  float cst = 0.f;                     // lay0: c1, lay1: c0
  __syncthreads();                     // zeros + x prefill visible

  // ---- prologue: L0(t=0); U0 and h-part of U1 are zeros, x(0) from xfS ----
  {
    const bfrag U0 = *(const bfrag*)(hB + lane * 16);                  // zeros
    const char* pU1p = (quad == 3) ? ((const char*)xfS + c16 * 16)
                                   : (hB + 1024 + lane * 16);          // zeros
    const bfrag U1 = *(const bfrag*)pU1p;
    const float x8v = x8S[b];
    ffrag a0 = MFMA(B0h[0], U0, bias0f);
    a0 = MFMA(B0h[1], U1, a0);
    a0 = MFMA(B0l[0], U0, a0);
    a0 = MFMA(B0l[1], U1, a0);
    float s0[4];
    #pragma unroll
    for (int r = 0; r < 4; ++r) s0[r] = a0[r] + dpp8(a0[r]);
    if (lay) {
      const float gi = fmaf(wx8a[0], x8v, s0[0]);
      const float gf = fmaf(wx8a[1], x8v, s0[1]);
      const float gg = fmaf(wx8a[2], x8v, s0[2]);
      const float go = fmaf(wx8a[3], x8v, s0[3]);
      const float iv = sigm_f(gi), fv = sigm_f(gf);
      const float gv = tanh_f(gg), ov = sigm_f(go);
      cst = fmaf(fv, cst, iv * gv);
      const float hv = ov * tanh_f(cst);
      short hs, hl; split_bf16t(hv, hs, hl);
      hp1[0] = hs; hp1[64] = hl;       // h0(0) -> sB[1]
    }
    __syncthreads();
  }

#define REGION(RR, L0PART, LASTR)                                               \
  {                                                                             \
    const bfrag U0 = *(const bfrag*)pU0_##RR;                                   \
    const bfrag U1 = *(const bfrag*)pU1_##RR;                                   \
    const bfrag H0 = *(const bfrag*)pH0_##RR;                                   \
    const bfrag H1 = *(const bfrag*)pH1_##RR;                                   \
    ffrag a0a, a0b;                                                             \
    float x8v = 0.0f;                                                           \
    if (L0PART) x8v = *(const float*)px8_##RR;                                  \
    __builtin_amdgcn_s_setprio(1);                                              \
    if (L0PART) {                                                               \
      /* two independent 2-chains instead of one 4-chain */                     \
      a0a = MFMA(B0h[0], U0, bias0f);                                           \
      a0b = MFMA(B0l[0], U0, zerof);                                            \
      a0a = MFMA(B0h[1], U1, a0a);                                              \
      a0b = MFMA(B0l[1], U1, a0b);                                              \
    }                                                                           \
    /* L1: hi-weight passes; aU folded into aH via the C operand (free) */      \
    ffrag aH = MFMA(Bhh[0], H0, bias1f);                                        \
    aH = MFMA(Bhh[1], H1, aH);                                                  \
    aH = MFMA(Buh[0], U0, aH);                                                  \
    aH = MFMA(Buh[1], U1, aH);                                                  \
    __builtin_amdgcn_s_setprio(0);                                              \
    if (!LASTR) {                                                               \
      /* lane^8 partner has opposite lay: one dpp-add gives each lane its sum */\
      float sv[4];                                                              \
      _Pragma("unroll")                                                         \
      for (int r = 0; r < 4; ++r) {                                             \
        const float t0 = a0a[r] + a0b[r];                                       \
        const float uu = lay ? t0 : aH[r];                                      \
        const float vv = lay ? aH[r] : t0;                                      \
        sv[r] = uu + dpp8(vv);                                                  \
      }                                                                         \
      const float gi = fmaf(wx8a[0], x8v, sv[0]);                               \
      const float gf = fmaf(wx8a[1], x8v, sv[1]);                               \
      const float gg = fmaf(wx8a[2], x8v, sv[2]);                               \
      const float go = fmaf(wx8a[3], x8v, sv[3]);                               \
      const float iv = sigm_f(gi), fv = sigm_f(gf);                             \
      const float gv = tanh_f(gg), ov = sigm_f(go);                             \
      cst = fmaf(fv, cst, iv * gv);                                             \
      const float hv = ov * tanh_f(cst);                                        \
      short hs, hl; split_bf16t(hv, hs, hl);                                    \
      short* hb2 = (RR == 0) ? hp0 : hp1;                                       \
      hb2[0] = hs; hb2[64] = hl;                                                \
    } else {                                                                    \
      float s1[4];                                                              \
      _Pragma("unroll")                                                         \
      for (int r = 0; r < 4; ++r) s1[r] = aH[r] + dpp8(aH[r]);                  \
      if (lay == 0) {                                                           \
        const float iv = sigm_f(s1[0]), fv = sigm_f(s1[1]);                     \
        const float gv = tanh_f(s1[2]), ov = sigm_f(s1[3]);                     \
        cst = fmaf(fv, cst, iv * gv);                                           \
        sF[b * H + j4] = ov * tanh_f(cst);                                      \
      }                                                                         \
    }                                                                           \
    __syncthreads();                                                            \
  }

  // main: 255 iters x 2 regions (t=1..510), then t=511, then L1-only tail
  for (int it = 0; it < 255; ++it) {
    REGION(0, 1, 0)
    REGION(1, 1, 0)
    pU1_0 += incU1; pU1_1 += incU1;
    px8_0 += 64;    px8_1 += 64;
  }
  REGION(0, 1, 0)
  // pU1_1 would be one timestep past xfS (t=512): pull it back in-bounds.
  // Data is irrelevant (Buh rows k>=56 are zero) but OOB garbage risks 0*Inf=NaN.
  pU1_1 -= incU1;
  REGION(1, 0, 1)
#undef REGION

  // ---- FC head on final h1 ----
  if (tid < 28 * BG) {
    const int m  = tid >> 3;
    const int bb = tid & 7;
    float acc = fc1_b[m];
    const float4* w4 = (const float4*)(fc1_w + m * H);
    const float4* h4 = (const float4*)(sF + bb * H);
    #pragma unroll
    for (int qq = 0; qq < H / 4; ++qq) {
      const float4 wv4 = w4[qq], hv4 = h4[qq];
      acc = fmaf(wv4.x, hv4.x, acc);
      acc = fmaf(wv4.y, hv4.y, acc);
      acc = fmaf(wv4.z, hv4.z, acc);
      acc = fmaf(wv4.w, hv4.w, acc);
    }
    sY[bb * 28 + m] = fmaxf(acc, 0.0f);
  }
  __syncthreads();
  if (tid < BG) {
    float acc = fc2_b[0];
    #pragma unroll
    for (int m = 0; m < 28; ++m)
      acc = fmaf(fc2_w[m], sY[tid * 28 + m], acc);
    out[blockIdx.x * BG + tid] = acc;
  }
}

extern "C" void kernel_launch(void* const* d_in, const int* in_sizes, int n_in,
                              void* d_out, int out_size, void* d_ws, size_t ws_size,
                              hipStream_t stream)
{
  const float* x     = (const float*)d_in[0];
  const float* w_ih0 = (const float*)d_in[1];
  const float* w_hh0 = (const float*)d_in[2];
  const float* b_ih0 = (const float*)d_in[3];
  const float* b_hh0 = (const float*)d_in[4];
  const float* w_ih1 = (const float*)d_in[5];
  const float* w_hh1 = (const float*)d_in[6];
  const float* b_ih1 = (const float*)d_in[7];
  const float* b_hh1 = (const float*)d_in[8];
  const float* fc1_w = (const float*)d_in[9];
  const float* fc1_b = (const float*)d_in[10];
  const float* fc2_w = (const float*)d_in[11];
  const float* fc2_b = (const float*)d_in[12];
  float* out = (float*)d_out;

  lstm_mfma10<<<NBLK, NTH, 0, stream>>>(
      x, w_ih0, w_hh0, b_ih0, b_hh0, w_ih1, w_hh1, b_ih1, b_hh1,
      fc1_w, fc1_b, fc2_w, fc2_b, out);
}